// Round 3
// baseline (1274.162 us; speedup 1.0000x reference)
//
#include <hip/hip_runtime.h>
#include <hip/hip_bf16.h>

typedef __bf16 bf16_t;
typedef __bf16 bf16x8 __attribute__((ext_vector_type(8)));
typedef float  f32x4  __attribute__((ext_vector_type(4)));

#define N_NODES 100000
#define N_EDGES 1600000
#define IN_C    128
#define OUT_C   64
#define EDGE_D  64
#define NB_SCAN 98   // ceil(100000 / 1024)

// ---------------- Kernel A: node GEMM (k,q,v,skip) ----------------
__global__ __launch_bounds__(256) void node_gemm_kernel(
    const float* __restrict__ x,
    const float* __restrict__ Wk, const float* __restrict__ bk,
    const float* __restrict__ Wq, const float* __restrict__ bq,
    const float* __restrict__ Wv, const float* __restrict__ bv,
    const float* __restrict__ Ws, const float* __restrict__ bs,
    bf16_t* __restrict__ kqv,   // [3][N][64] bf16
    float*  __restrict__ agg)   // [N][64] f32 (skip-init)
{
    const int w  = threadIdx.x >> 6;
    const int l  = threadIdx.x & 63;
    const int lr = l & 15;
    const int lg = l >> 4;

    const float* W; const float* b;
    if      (w == 0) { W = Wk; b = bk; }
    else if (w == 1) { W = Wq; b = bq; }
    else if (w == 2) { W = Wv; b = bv; }
    else             { W = Ws; b = bs; }

    bf16x8 Bf[4][4];
    #pragma unroll
    for (int ct = 0; ct < 4; ++ct)
        #pragma unroll
        for (int ks = 0; ks < 4; ++ks)
            #pragma unroll
            for (int j = 0; j < 8; ++j)
                Bf[ct][ks][j] = (bf16_t)W[(ks*32 + lg*8 + j)*OUT_C + ct*16 + lr];

    float biasv[4];
    #pragma unroll
    for (int ct = 0; ct < 4; ++ct) biasv[ct] = b[ct*16 + lr];

    const int NTILES = N_NODES / 32;  // 3125
    for (int tile = blockIdx.x; tile < NTILES; tile += gridDim.x) {
        const int n0 = tile * 32;
        f32x4 acc[2][4];
        #pragma unroll
        for (int rt = 0; rt < 2; ++rt)
            #pragma unroll
            for (int ct = 0; ct < 4; ++ct)
                acc[rt][ct] = (f32x4){0.f, 0.f, 0.f, 0.f};

        #pragma unroll
        for (int ks = 0; ks < 4; ++ks) {
            const float* p0 = x + (size_t)(n0 + lr)      * IN_C + ks*32 + lg*8;
            const float* p1 = x + (size_t)(n0 + 16 + lr) * IN_C + ks*32 + lg*8;
            f32x4 v00 = *reinterpret_cast<const f32x4*>(p0);
            f32x4 v01 = *reinterpret_cast<const f32x4*>(p0 + 4);
            f32x4 v10 = *reinterpret_cast<const f32x4*>(p1);
            f32x4 v11 = *reinterpret_cast<const f32x4*>(p1 + 4);
            bf16x8 a0, a1;
            #pragma unroll
            for (int j = 0; j < 4; ++j) {
                a0[j] = (bf16_t)v00[j]; a0[4+j] = (bf16_t)v01[j];
                a1[j] = (bf16_t)v10[j]; a1[4+j] = (bf16_t)v11[j];
            }
            #pragma unroll
            for (int ct = 0; ct < 4; ++ct) {
                acc[0][ct] = __builtin_amdgcn_mfma_f32_16x16x32_bf16(a0, Bf[ct][ks], acc[0][ct], 0, 0, 0);
                acc[1][ct] = __builtin_amdgcn_mfma_f32_16x16x32_bf16(a1, Bf[ct][ks], acc[1][ct], 0, 0, 0);
            }
        }

        #pragma unroll
        for (int rt = 0; rt < 2; ++rt)
            #pragma unroll
            for (int ct = 0; ct < 4; ++ct)
                #pragma unroll
                for (int r = 0; r < 4; ++r) {
                    const int row = n0 + rt*16 + lg*4 + r;
                    const int col = ct*16 + lr;
                    const float val = acc[rt][ct][r] + biasv[ct];
                    if (w < 3) kqv[(size_t)w * N_NODES * OUT_C + (size_t)row * OUT_C + col] = (bf16_t)val;
                    else       agg[(size_t)row * OUT_C + col] = val;
                }
    }
}

// ---------------- counting sort by dst ----------------
__global__ __launch_bounds__(256) void zero_cnt_kernel(unsigned* __restrict__ cnt) {
    const int i0 = (blockIdx.x * 256 + threadIdx.x) * 4;
    #pragma unroll
    for (int j = 0; j < 4; ++j)
        if (i0 + j < N_NODES) cnt[i0 + j] = 0u;
}

__global__ __launch_bounds__(256) void hist_kernel(const int* __restrict__ dst,
                                                   unsigned* __restrict__ cnt) {
    const int i = (blockIdx.x * 256 + threadIdx.x) * 4;
    if (i < N_EDGES) {
        int4 d = *reinterpret_cast<const int4*>(dst + i);
        atomicAdd(&cnt[d.x], 1u);
        atomicAdd(&cnt[d.y], 1u);
        atomicAdd(&cnt[d.z], 1u);
        atomicAdd(&cnt[d.w], 1u);
    }
}

__global__ __launch_bounds__(256) void scan1_kernel(const unsigned* __restrict__ cnt,
                                                    unsigned* __restrict__ bsum) {
    __shared__ unsigned s[256];
    const int b = blockIdx.x, t = threadIdx.x;
    const int i0 = b * 1024 + t * 4;
    unsigned x = 0;
    #pragma unroll
    for (int j = 0; j < 4; ++j)
        if (i0 + j < N_NODES) x += cnt[i0 + j];
    s[t] = x; __syncthreads();
    for (int d = 128; d > 0; d >>= 1) {
        if (t < d) s[t] += s[t + d];
        __syncthreads();
    }
    if (t == 0) bsum[b] = s[0];
}

__global__ void scan2_kernel(unsigned* __restrict__ bsum, unsigned* __restrict__ segoff) {
    if (threadIdx.x == 0 && blockIdx.x == 0) {
        unsigned run = 0;
        for (int i = 0; i < NB_SCAN; ++i) { unsigned v = bsum[i]; bsum[i] = run; run += v; }
        segoff[N_NODES] = N_EDGES;
    }
}

__global__ __launch_bounds__(256) void scan3_kernel(const unsigned* __restrict__ cnt,
                                                    const unsigned* __restrict__ bsum,
                                                    unsigned* __restrict__ segoff,
                                                    unsigned* __restrict__ cursor) {
    __shared__ unsigned s[256];
    const int b = blockIdx.x, t = threadIdx.x;
    const int i0 = b * 1024 + t * 4;
    unsigned v[4]; unsigned x = 0;
    #pragma unroll
    for (int j = 0; j < 4; ++j) {
        v[j] = (i0 + j < N_NODES) ? cnt[i0 + j] : 0u;
        x += v[j];
    }
    s[t] = x; __syncthreads();
    for (int d = 1; d < 256; d <<= 1) {
        unsigned y = (t >= d) ? s[t - d] : 0u;
        __syncthreads();
        s[t] += y;
        __syncthreads();
    }
    unsigned excl = s[t] - x + bsum[b];
    #pragma unroll
    for (int j = 0; j < 4; ++j)
        if (i0 + j < N_NODES) {
            segoff[i0 + j] = excl;
            cursor[i0 + j] = excl;
            excl += v[j];
        }
}

__global__ __launch_bounds__(256) void scatter_kernel(const int* __restrict__ dst,
                                                      unsigned* __restrict__ cursor,
                                                      unsigned* __restrict__ sorted) {
    const int i = (blockIdx.x * 256 + threadIdx.x) * 4;
    if (i < N_EDGES) {
        int4 d = *reinterpret_cast<const int4*>(dst + i);
        sorted[atomicAdd(&cursor[d.x], 1u)] = (unsigned)(i + 0);
        sorted[atomicAdd(&cursor[d.y], 1u)] = (unsigned)(i + 1);
        sorted[atomicAdd(&cursor[d.z], 1u)] = (unsigned)(i + 2);
        sorted[atomicAdd(&cursor[d.w], 1u)] = (unsigned)(i + 3);
    }
}

// ---------------- Kernel B: CSR edge kernel (wave per dst, no atomics) ----------------
__global__ __launch_bounds__(256) void edge_csr_kernel(
    const float* __restrict__ ea,
    const int*   __restrict__ ei,      // [2][E]: row0=src
    const float* __restrict__ We, const float* __restrict__ be,
    const bf16_t* __restrict__ kqv,
    const unsigned* __restrict__ segoff,
    const unsigned* __restrict__ sorted,
    float* __restrict__ agg,
    float* __restrict__ out_ea)
{
    const int l  = threadIdx.x & 63;
    const int lr = l & 15;
    const int lg = l >> 4;
    const int wid0 = blockIdx.x * 4 + (threadIdx.x >> 6);
    const int nw   = gridDim.x * 4;

    bf16x8 Bf[4][2];
    #pragma unroll
    for (int ct = 0; ct < 4; ++ct)
        #pragma unroll
        for (int ks = 0; ks < 2; ++ks)
            #pragma unroll
            for (int j = 0; j < 8; ++j)
                Bf[ct][ks][j] = (bf16_t)We[(ks*32 + lg*8 + j)*OUT_C + ct*16 + lr];

    float bev[4];
    #pragma unroll
    for (int ct = 0; ct < 4; ++ct) bev[ct] = be[ct*16 + lr];

    const bf16_t* kT = kqv;
    const bf16_t* qT = kqv + (size_t)N_NODES * OUT_C;
    const bf16_t* vT = kqv + (size_t)2 * N_NODES * OUT_C;

    for (int d = wid0; d < N_NODES; d += nw) {
        const unsigned start = segoff[d];
        const unsigned end   = segoff[d + 1];
        if (start == end) continue;

        // k[d] row + edge bias, per-lane cols ct*16+lr (constant over the segment)
        float kd[4];
        #pragma unroll
        for (int ct = 0; ct < 4; ++ct)
            kd[ct] = (float)kT[(size_t)d * OUT_C + ct*16 + lr] + bev[ct];

        f32x4 acc[4];
        #pragma unroll
        for (int ct = 0; ct < 4; ++ct) acc[ct] = (f32x4){0.f, 0.f, 0.f, 0.f};

        for (unsigned base = start; base < end; base += 16) {
            // A-fragment rows: slot = lr; fused out_ea copy (each edge row once)
            const unsigned iA = base + lr;
            const bool vA = iA < end;
            const int eidA = (int)sorted[vA ? iA : (end - 1)];
            bf16x8 a[2];
            #pragma unroll
            for (int ks = 0; ks < 2; ++ks) {
                const size_t off = (size_t)eidA * EDGE_D + ks*32 + lg*8;
                f32x4 v0 = *reinterpret_cast<const f32x4*>(ea + off);
                f32x4 v1 = *reinterpret_cast<const f32x4*>(ea + off + 4);
                if (vA) {
                    *reinterpret_cast<f32x4*>(out_ea + off)     = v0;
                    *reinterpret_cast<f32x4*>(out_ea + off + 4) = v1;
                }
                #pragma unroll
                for (int j = 0; j < 4; ++j) { a[ks][j] = (bf16_t)v0[j]; a[ks][4+j] = (bf16_t)v1[j]; }
            }

            f32x4 ep[4];
            #pragma unroll
            for (int ct = 0; ct < 4; ++ct) {
                f32x4 z = (f32x4){0.f, 0.f, 0.f, 0.f};
                z = __builtin_amdgcn_mfma_f32_16x16x32_bf16(a[0], Bf[ct][0], z, 0, 0, 0);
                ep[ct] = __builtin_amdgcn_mfma_f32_16x16x32_bf16(a[1], Bf[ct][1], z, 0, 0, 0);
            }

            // epilogue: slot s = lg*4 + r (C layout), gather q/v, gate, accumulate
            #pragma unroll
            for (int r = 0; r < 4; ++r) {
                const unsigned is = base + lg*4 + r;
                const bool vv = is < end;
                const int se  = (int)sorted[vv ? is : (end - 1)];
                const int src = ei[se];
                #pragma unroll
                for (int ct = 0; ct < 4; ++ct) {
                    const int col = ct*16 + lr;
                    const float qs = (float)qT[(size_t)src * OUT_C + col];
                    const float vs = (float)vT[(size_t)src * OUT_C + col];
                    const float z  = kd[ct] + qs + ep[ct][r];
                    const float g  = 1.f / (1.f + __expf(-z));
                    if (vv) acc[ct][r] += g * vs;
                }
            }
        }

        // reduce over r (in-lane) then across lane groups (lg), write once
        #pragma unroll
        for (int ct = 0; ct < 4; ++ct) {
            float p = acc[ct][0] + acc[ct][1] + acc[ct][2] + acc[ct][3];
            p += __shfl_xor(p, 16);
            p += __shfl_xor(p, 32);
            if (lg == 0)
                agg[(size_t)d * OUT_C + ct*16 + lr] += p;
        }
    }
}

// ---------------- Kernel C: finalize ----------------
__global__ __launch_bounds__(256) void finalize_kernel(
    const float* __restrict__ agg,
    const float* __restrict__ u,
    float* __restrict__ out_node,
    float* __restrict__ out_u)
{
    const int gid   = blockIdx.x * blockDim.x + threadIdx.x;
    const int total = N_NODES * OUT_C / 4;
    for (int i = gid; i < total; i += gridDim.x * blockDim.x) {
        f32x4 v = *reinterpret_cast<const f32x4*>(agg + (size_t)i * 4);
        f32x4 o;
        #pragma unroll
        for (int j = 0; j < 4; ++j) o[j] = v[j] > 0.f ? v[j] : 0.f;
        *reinterpret_cast<f32x4*>(out_node + (size_t)i * 4) = o;
    }
    if (gid < 64) out_u[gid] = u[gid];
}

extern "C" void kernel_launch(void* const* d_in, const int* in_sizes, int n_in,
                              void* d_out, int out_size, void* d_ws, size_t ws_size,
                              hipStream_t stream) {
    const float* x  = (const float*)d_in[0];
    const int*   ei = (const int*)  d_in[1];
    const float* ea = (const float*)d_in[2];
    const float* u  = (const float*)d_in[3];
    const float* Wk = (const float*)d_in[4];
    const float* bk = (const float*)d_in[5];
    const float* Wq = (const float*)d_in[6];
    const float* bq = (const float*)d_in[7];
    const float* Wv = (const float*)d_in[8];
    const float* bv = (const float*)d_in[9];
    const float* We = (const float*)d_in[10];
    const float* be = (const float*)d_in[11];
    const float* Ws = (const float*)d_in[12];
    const float* bs = (const float*)d_in[13];

    float* out      = (float*)d_out;
    float* out_node = out;
    float* out_ea   = out + (size_t)N_NODES * OUT_C;
    float* out_u    = out + (size_t)N_NODES * OUT_C + (size_t)N_EDGES * EDGE_D;

    // ws layout
    char* w = (char*)d_ws;
    bf16_t*   kqv    = (bf16_t*)w;                                   // 38,400,000 B
    float*    agg    = (float*)(w + 38400000);                       // 25,600,000 B
    unsigned* cnt    = (unsigned*)(w + 64000000);                    //    400,000 B (hist -> cursor)
    unsigned* segoff = (unsigned*)(w + 64400000);                    //    400,004 B
    unsigned* bsum   = (unsigned*)(w + 64800016);                    //        512 B
    unsigned* sorted = (unsigned*)(w + 64800528);                    //  6,400,000 B

    const int* dst = ei + N_EDGES;  // ei[1][*]

    node_gemm_kernel<<<1024, 256, 0, stream>>>(x, Wk, bk, Wq, bq, Wv, bv, Ws, bs, kqv, agg);
    zero_cnt_kernel<<<98, 256, 0, stream>>>(cnt);
    hist_kernel<<<1563, 256, 0, stream>>>(dst, cnt);
    scan1_kernel<<<NB_SCAN, 256, 0, stream>>>(cnt, bsum);
    scan2_kernel<<<1, 64, 0, stream>>>(bsum, segoff);
    scan3_kernel<<<NB_SCAN, 256, 0, stream>>>(cnt, bsum, segoff, cnt /*cursor*/);
    scatter_kernel<<<1563, 256, 0, stream>>>(dst, cnt, sorted);
    edge_csr_kernel<<<2048, 256, 0, stream>>>(ea, ei, We, be, kqv, segoff, sorted, agg, out_ea);
    finalize_kernel<<<2048, 256, 0, stream>>>(agg, u, out_node, out_u);
}

// Round 4
// 724.823 us; speedup vs baseline: 1.7579x; 1.7579x over previous
//
#include <hip/hip_runtime.h>
#include <hip/hip_bf16.h>

typedef __bf16 bf16_t;
typedef __bf16 bf16x8 __attribute__((ext_vector_type(8)));
typedef float  f32x4  __attribute__((ext_vector_type(4)));

#define N_NODES 100000
#define N_EDGES 1600000
#define IN_C    128
#define OUT_C   64
#define EDGE_D  64
#define NB_SCAN 98   // ceil(100000 / 1024)

// ---------------- Kernel A: node GEMM (k,q,v,skip) ----------------
__global__ __launch_bounds__(256) void node_gemm_kernel(
    const float* __restrict__ x,
    const float* __restrict__ Wk, const float* __restrict__ bk,
    const float* __restrict__ Wq, const float* __restrict__ bq,
    const float* __restrict__ Wv, const float* __restrict__ bv,
    const float* __restrict__ Ws, const float* __restrict__ bs,
    bf16_t* __restrict__ kqv,   // [3][N][64] bf16
    float*  __restrict__ agg)   // [N][64] f32 (skip-init)
{
    const int w  = threadIdx.x >> 6;
    const int l  = threadIdx.x & 63;
    const int lr = l & 15;
    const int lg = l >> 4;

    const float* W; const float* b;
    if      (w == 0) { W = Wk; b = bk; }
    else if (w == 1) { W = Wq; b = bq; }
    else if (w == 2) { W = Wv; b = bv; }
    else             { W = Ws; b = bs; }

    bf16x8 Bf[4][4];
    #pragma unroll
    for (int ct = 0; ct < 4; ++ct)
        #pragma unroll
        for (int ks = 0; ks < 4; ++ks)
            #pragma unroll
            for (int j = 0; j < 8; ++j)
                Bf[ct][ks][j] = (bf16_t)W[(ks*32 + lg*8 + j)*OUT_C + ct*16 + lr];

    float biasv[4];
    #pragma unroll
    for (int ct = 0; ct < 4; ++ct) biasv[ct] = b[ct*16 + lr];

    const int NTILES = N_NODES / 32;  // 3125
    for (int tile = blockIdx.x; tile < NTILES; tile += gridDim.x) {
        const int n0 = tile * 32;
        f32x4 acc[2][4];
        #pragma unroll
        for (int rt = 0; rt < 2; ++rt)
            #pragma unroll
            for (int ct = 0; ct < 4; ++ct)
                acc[rt][ct] = (f32x4){0.f, 0.f, 0.f, 0.f};

        #pragma unroll
        for (int ks = 0; ks < 4; ++ks) {
            const float* p0 = x + (size_t)(n0 + lr)      * IN_C + ks*32 + lg*8;
            const float* p1 = x + (size_t)(n0 + 16 + lr) * IN_C + ks*32 + lg*8;
            f32x4 v00 = *reinterpret_cast<const f32x4*>(p0);
            f32x4 v01 = *reinterpret_cast<const f32x4*>(p0 + 4);
            f32x4 v10 = *reinterpret_cast<const f32x4*>(p1);
            f32x4 v11 = *reinterpret_cast<const f32x4*>(p1 + 4);
            bf16x8 a0, a1;
            #pragma unroll
            for (int j = 0; j < 4; ++j) {
                a0[j] = (bf16_t)v00[j]; a0[4+j] = (bf16_t)v01[j];
                a1[j] = (bf16_t)v10[j]; a1[4+j] = (bf16_t)v11[j];
            }
            #pragma unroll
            for (int ct = 0; ct < 4; ++ct) {
                acc[0][ct] = __builtin_amdgcn_mfma_f32_16x16x32_bf16(a0, Bf[ct][ks], acc[0][ct], 0, 0, 0);
                acc[1][ct] = __builtin_amdgcn_mfma_f32_16x16x32_bf16(a1, Bf[ct][ks], acc[1][ct], 0, 0, 0);
            }
        }

        #pragma unroll
        for (int rt = 0; rt < 2; ++rt)
            #pragma unroll
            for (int ct = 0; ct < 4; ++ct)
                #pragma unroll
                for (int r = 0; r < 4; ++r) {
                    const int row = n0 + rt*16 + lg*4 + r;
                    const int col = ct*16 + lr;
                    const float val = acc[rt][ct][r] + biasv[ct];
                    if (w < 3) kqv[(size_t)w * N_NODES * OUT_C + (size_t)row * OUT_C + col] = (bf16_t)val;
                    else       agg[(size_t)row * OUT_C + col] = val;
                }
    }
}

// ---------------- counting sort by dst ----------------
__global__ __launch_bounds__(256) void zero_cnt_kernel(unsigned* __restrict__ cnt) {
    const int i0 = (blockIdx.x * 256 + threadIdx.x) * 4;
    #pragma unroll
    for (int j = 0; j < 4; ++j)
        if (i0 + j < N_NODES) cnt[i0 + j] = 0u;
}

__global__ __launch_bounds__(256) void hist_kernel(const int* __restrict__ dst,
                                                   unsigned* __restrict__ cnt) {
    const int i = (blockIdx.x * 256 + threadIdx.x) * 4;
    if (i < N_EDGES) {
        int4 d = *reinterpret_cast<const int4*>(dst + i);
        atomicAdd(&cnt[d.x], 1u);
        atomicAdd(&cnt[d.y], 1u);
        atomicAdd(&cnt[d.z], 1u);
        atomicAdd(&cnt[d.w], 1u);
    }
}

__global__ __launch_bounds__(256) void scan1_kernel(const unsigned* __restrict__ cnt,
                                                    unsigned* __restrict__ bsum) {
    __shared__ unsigned s[256];
    const int b = blockIdx.x, t = threadIdx.x;
    const int i0 = b * 1024 + t * 4;
    unsigned x = 0;
    #pragma unroll
    for (int j = 0; j < 4; ++j)
        if (i0 + j < N_NODES) x += cnt[i0 + j];
    s[t] = x; __syncthreads();
    for (int d = 128; d > 0; d >>= 1) {
        if (t < d) s[t] += s[t + d];
        __syncthreads();
    }
    if (t == 0) bsum[b] = s[0];
}

__global__ void scan2_kernel(unsigned* __restrict__ bsum) {
    if (threadIdx.x == 0 && blockIdx.x == 0) {
        unsigned run = 0;
        for (int i = 0; i < NB_SCAN; ++i) { unsigned v = bsum[i]; bsum[i] = run; run += v; }
    }
}

__global__ __launch_bounds__(256) void scan3_kernel(const unsigned* __restrict__ cnt,
                                                    const unsigned* __restrict__ bsum,
                                                    unsigned* __restrict__ cursor) {
    __shared__ unsigned s[256];
    const int b = blockIdx.x, t = threadIdx.x;
    const int i0 = b * 1024 + t * 4;
    unsigned v[4]; unsigned x = 0;
    #pragma unroll
    for (int j = 0; j < 4; ++j) {
        v[j] = (i0 + j < N_NODES) ? cnt[i0 + j] : 0u;
        x += v[j];
    }
    s[t] = x; __syncthreads();
    for (int d = 1; d < 256; d <<= 1) {
        unsigned y = (t >= d) ? s[t - d] : 0u;
        __syncthreads();
        s[t] += y;
        __syncthreads();
    }
    unsigned excl = s[t] - x + bsum[b];
    #pragma unroll
    for (int j = 0; j < 4; ++j)
        if (i0 + j < N_NODES) { cursor[i0 + j] = excl; excl += v[j]; }
}

// scatter: sorted16[pos] = {eid, src, dst, 0} — all edge metadata in one 16B record
__global__ __launch_bounds__(256) void scatter_kernel(const int* __restrict__ ei,
                                                      unsigned* __restrict__ cursor,
                                                      int4* __restrict__ sorted16) {
    const int i = (blockIdx.x * 256 + threadIdx.x) * 4;
    if (i < N_EDGES) {
        int4 s = *reinterpret_cast<const int4*>(ei + i);            // src
        int4 d = *reinterpret_cast<const int4*>(ei + N_EDGES + i);  // dst
        sorted16[atomicAdd(&cursor[d.x], 1u)] = make_int4(i + 0, s.x, d.x, 0);
        sorted16[atomicAdd(&cursor[d.y], 1u)] = make_int4(i + 1, s.y, d.y, 0);
        sorted16[atomicAdd(&cursor[d.z], 1u)] = make_int4(i + 2, s.z, d.z, 0);
        sorted16[atomicAdd(&cursor[d.w], 1u)] = make_int4(i + 3, s.w, d.w, 0);
    }
}

// ---------------- Kernel B: dense tiles over dst-sorted edges + in-wave
// segmented reduction; atomics only at segment boundaries (~2 per tile) ------
__global__ __launch_bounds__(256) void edge_seg_kernel(
    const float* __restrict__ ea,
    const int4*  __restrict__ sorted16,
    const float* __restrict__ We, const float* __restrict__ be,
    const bf16_t* __restrict__ kqv,
    float* __restrict__ agg,
    float* __restrict__ out_ea)
{
    const int l  = threadIdx.x & 63;
    const int lr = l & 15;
    const int lg = l >> 4;
    const int wid0 = blockIdx.x * 4 + (threadIdx.x >> 6);
    const int nw   = gridDim.x * 4;

    bf16x8 Bf[4][2];
    #pragma unroll
    for (int ct = 0; ct < 4; ++ct)
        #pragma unroll
        for (int ks = 0; ks < 2; ++ks)
            #pragma unroll
            for (int j = 0; j < 8; ++j)
                Bf[ct][ks][j] = (bf16_t)We[(ks*32 + lg*8 + j)*OUT_C + ct*16 + lr];

    float bev[4];
    #pragma unroll
    for (int ct = 0; ct < 4; ++ct) bev[ct] = be[ct*16 + lr];

    const bf16_t* kT = kqv;
    const bf16_t* qT = kqv + (size_t)N_NODES * OUT_C;
    const bf16_t* vT = kqv + (size_t)2 * N_NODES * OUT_C;

    const int NT = N_EDGES / 16;  // 100000 tiles of 16 sorted edges
    for (int t = wid0; t < NT; t += nw) {
        const int e0 = t * 16;

        // ---- A-fragment (slot = lr) + fused out_ea copy ----
        const int eidA = sorted16[e0 + lr].x;
        bf16x8 a[2];
        #pragma unroll
        for (int ks = 0; ks < 2; ++ks) {
            const size_t off = (size_t)eidA * EDGE_D + ks*32 + lg*8;
            f32x4 v0 = *reinterpret_cast<const f32x4*>(ea + off);
            f32x4 v1 = *reinterpret_cast<const f32x4*>(ea + off + 4);
            *reinterpret_cast<f32x4*>(out_ea + off)     = v0;
            *reinterpret_cast<f32x4*>(out_ea + off + 4) = v1;
            #pragma unroll
            for (int j = 0; j < 4; ++j) { a[ks][j] = (bf16_t)v0[j]; a[ks][4+j] = (bf16_t)v1[j]; }
        }

        f32x4 ep[4];
        #pragma unroll
        for (int ct = 0; ct < 4; ++ct) {
            f32x4 z = (f32x4){0.f, 0.f, 0.f, 0.f};
            z = __builtin_amdgcn_mfma_f32_16x16x32_bf16(a[0], Bf[ct][0], z, 0, 0, 0);
            ep[ct] = __builtin_amdgcn_mfma_f32_16x16x32_bf16(a[1], Bf[ct][1], z, 0, 0, 0);
        }

        // ---- epilogue slots s = lg*4 + r ----
        int4 meta[4];
        #pragma unroll
        for (int r = 0; r < 4; ++r) meta[r] = sorted16[e0 + lg*4 + r];
        const int d0 = meta[0].z, d1 = meta[1].z, d2 = meta[2].z, d3 = meta[3].z;

        float val[4][4];  // [r][ct]
        #pragma unroll
        for (int r = 0; r < 4; ++r) {
            const int src = meta[r].y;
            const int dstv = meta[r].z;
            #pragma unroll
            for (int ct = 0; ct < 4; ++ct) {
                const int col = ct*16 + lr;
                const float kd = (float)kT[(size_t)dstv * OUT_C + col];
                const float qs = (float)qT[(size_t)src  * OUT_C + col];
                const float vs = (float)vT[(size_t)src  * OUT_C + col];
                const float z  = kd + bev[ct] + qs + ep[ct][r];
                const float g  = 1.f / (1.f + __expf(-z));
                val[r][ct] = g * vs;
            }
        }

        // ---- in-lane inclusive segmented scan over r (dsts sorted) ----
        #pragma unroll
        for (int ct = 0; ct < 4; ++ct) {
            if (d1 == d0) val[1][ct] += val[0][ct];
            if (d2 == d1) val[2][ct] += val[1][ct];
            if (d3 == d2) val[3][ct] += val[2][ct];
        }

        // ---- cross-lane-group segmented scan on (S, B) monoid ----
        const int prev_d3 = __shfl(d3, l - 16);          // valid lg>0
        const int h  = (lg == 0) || (d0 != prev_d3);     // head at lane's slot 0
        int Bs = h || (d0 != d3);                        // lane contains a head
        float S[4];
        #pragma unroll
        for (int ct = 0; ct < 4; ++ct) S[ct] = val[3][ct];

        { // step o = 16 (1 lane group)
            float p0 = __shfl(S[0], l-16), p1 = __shfl(S[1], l-16),
                  p2 = __shfl(S[2], l-16), p3 = __shfl(S[3], l-16);
            int  pB = __shfl(Bs, l-16);
            if (lg >= 1) {
                if (!Bs) { S[0] += p0; S[1] += p1; S[2] += p2; S[3] += p3; }
                Bs |= pB;
            }
        }
        { // step o = 32 (2 lane groups)
            float p0 = __shfl(S[0], l-32), p1 = __shfl(S[1], l-32),
                  p2 = __shfl(S[2], l-32), p3 = __shfl(S[3], l-32);
            int  pB = __shfl(Bs, l-32);
            if (lg >= 2) {
                if (!Bs) { S[0] += p0; S[1] += p1; S[2] += p2; S[3] += p3; }
                Bs |= pB;
            }
        }

        // carry into this lane = inclusive result of previous lane group
        float C[4];
        #pragma unroll
        for (int ct = 0; ct < 4; ++ct) C[ct] = __shfl(S[ct], l - 16);

        if (!h) {  // h==1 covers lg==0; apply carry to this lane's leading run
            #pragma unroll
            for (int r = 0; r < 4; ++r)
                if (meta[r].z == d0) {
                    #pragma unroll
                    for (int ct = 0; ct < 4; ++ct) val[r][ct] += C[ct];
                }
        }

        // ---- segment-last flags; tile's final slot always flushes ----
        const int next_d0 = __shfl(d0, l + 16);          // valid lg<3
        bool lastR[4];
        lastR[0] = (d1 != d0);
        lastR[1] = (d2 != d1);
        lastR[2] = (d3 != d2);
        lastR[3] = (lg == 3) ? true : (next_d0 != d3);

        #pragma unroll
        for (int r = 0; r < 4; ++r) {
            if (lastR[r]) {
                float* row = agg + (size_t)meta[r].z * OUT_C + lr;
                #pragma unroll
                for (int ct = 0; ct < 4; ++ct)
                    atomicAdd(row + ct*16, val[r][ct]);
            }
        }
    }
}

// ---------------- Kernel C: finalize ----------------
__global__ __launch_bounds__(256) void finalize_kernel(
    const float* __restrict__ agg,
    const float* __restrict__ u,
    float* __restrict__ out_node,
    float* __restrict__ out_u)
{
    const int gid   = blockIdx.x * blockDim.x + threadIdx.x;
    const int total = N_NODES * OUT_C / 4;
    for (int i = gid; i < total; i += gridDim.x * blockDim.x) {
        f32x4 v = *reinterpret_cast<const f32x4*>(agg + (size_t)i * 4);
        f32x4 o;
        #pragma unroll
        for (int j = 0; j < 4; ++j) o[j] = v[j] > 0.f ? v[j] : 0.f;
        *reinterpret_cast<f32x4*>(out_node + (size_t)i * 4) = o;
    }
    if (gid < 64) out_u[gid] = u[gid];
}

extern "C" void kernel_launch(void* const* d_in, const int* in_sizes, int n_in,
                              void* d_out, int out_size, void* d_ws, size_t ws_size,
                              hipStream_t stream) {
    const float* x  = (const float*)d_in[0];
    const int*   ei = (const int*)  d_in[1];
    const float* ea = (const float*)d_in[2];
    const float* u  = (const float*)d_in[3];
    const float* Wk = (const float*)d_in[4];
    const float* bk = (const float*)d_in[5];
    const float* Wq = (const float*)d_in[6];
    const float* bq = (const float*)d_in[7];
    const float* Wv = (const float*)d_in[8];
    const float* bv = (const float*)d_in[9];
    const float* We = (const float*)d_in[10];
    const float* be = (const float*)d_in[11];
    const float* Ws = (const float*)d_in[12];
    const float* bs = (const float*)d_in[13];

    float* out      = (float*)d_out;
    float* out_node = out;
    float* out_ea   = out + (size_t)N_NODES * OUT_C;
    float* out_u    = out + (size_t)N_NODES * OUT_C + (size_t)N_EDGES * EDGE_D;

    // ws layout
    char* w = (char*)d_ws;
    bf16_t*   kqv      = (bf16_t*)w;                     // 38,400,000 B
    float*    agg      = (float*)(w + 38400000);         // 25,600,000 B -> 64,000,000
    unsigned* cnt      = (unsigned*)(w + 64000000);      //    400,000 B -> 64,400,000
    unsigned* bsum     = (unsigned*)(w + 64400000);      //        512 B -> 64,400,512
    int4*     sorted16 = (int4*)(w + 64400512);          // 25,600,000 B -> 90,000,512

    const int* dst = ei + N_EDGES;

    node_gemm_kernel<<<1024, 256, 0, stream>>>(x, Wk, bk, Wq, bq, Wv, bv, Ws, bs, kqv, agg);
    zero_cnt_kernel<<<98, 256, 0, stream>>>(cnt);
    hist_kernel<<<1563, 256, 0, stream>>>(dst, cnt);
    scan1_kernel<<<NB_SCAN, 256, 0, stream>>>(cnt, bsum);
    scan2_kernel<<<1, 64, 0, stream>>>(bsum);
    scan3_kernel<<<NB_SCAN, 256, 0, stream>>>(cnt, bsum, cnt /*cursor (in-place)*/);
    scatter_kernel<<<1563, 256, 0, stream>>>(ei, cnt, sorted16);
    edge_seg_kernel<<<2048, 256, 0, stream>>>(ea, sorted16, We, be, kqv, agg, out_ea);
    finalize_kernel<<<2048, 256, 0, stream>>>(agg, u, out_node, out_u);
}

// Round 5
// 515.122 us; speedup vs baseline: 2.4735x; 1.4071x over previous
//
#include <hip/hip_runtime.h>
#include <hip/hip_bf16.h>

typedef __bf16 bf16_t;
typedef __bf16 bf16x8 __attribute__((ext_vector_type(8)));
typedef float  f32x4  __attribute__((ext_vector_type(4)));

#define N_NODES 100000
#define N_EDGES 1600000
#define IN_C    128
#define OUT_C   64
#define EDGE_D  64
#define NB_SCAN 98   // ceil(100000 / 1024)

// ---------------- Kernel A: node GEMM (k,q,v,skip) ----------------
__global__ __launch_bounds__(256) void node_gemm_kernel(
    const float* __restrict__ x,
    const float* __restrict__ Wk, const float* __restrict__ bk,
    const float* __restrict__ Wq, const float* __restrict__ bq,
    const float* __restrict__ Wv, const float* __restrict__ bv,
    const float* __restrict__ Ws, const float* __restrict__ bs,
    bf16_t* __restrict__ kqv,   // [3][N][64] bf16
    float*  __restrict__ agg)   // [N][64] f32 (skip-init)
{
    const int w  = threadIdx.x >> 6;
    const int l  = threadIdx.x & 63;
    const int lr = l & 15;
    const int lg = l >> 4;

    const float* W; const float* b;
    if      (w == 0) { W = Wk; b = bk; }
    else if (w == 1) { W = Wq; b = bq; }
    else if (w == 2) { W = Wv; b = bv; }
    else             { W = Ws; b = bs; }

    bf16x8 Bf[4][4];
    #pragma unroll
    for (int ct = 0; ct < 4; ++ct)
        #pragma unroll
        for (int ks = 0; ks < 4; ++ks)
            #pragma unroll
            for (int j = 0; j < 8; ++j)
                Bf[ct][ks][j] = (bf16_t)W[(ks*32 + lg*8 + j)*OUT_C + ct*16 + lr];

    float biasv[4];
    #pragma unroll
    for (int ct = 0; ct < 4; ++ct) biasv[ct] = b[ct*16 + lr];

    const int NTILES = N_NODES / 32;  // 3125
    for (int tile = blockIdx.x; tile < NTILES; tile += gridDim.x) {
        const int n0 = tile * 32;
        f32x4 acc[2][4];
        #pragma unroll
        for (int rt = 0; rt < 2; ++rt)
            #pragma unroll
            for (int ct = 0; ct < 4; ++ct)
                acc[rt][ct] = (f32x4){0.f, 0.f, 0.f, 0.f};

        #pragma unroll
        for (int ks = 0; ks < 4; ++ks) {
            const float* p0 = x + (size_t)(n0 + lr)      * IN_C + ks*32 + lg*8;
            const float* p1 = x + (size_t)(n0 + 16 + lr) * IN_C + ks*32 + lg*8;
            f32x4 v00 = *reinterpret_cast<const f32x4*>(p0);
            f32x4 v01 = *reinterpret_cast<const f32x4*>(p0 + 4);
            f32x4 v10 = *reinterpret_cast<const f32x4*>(p1);
            f32x4 v11 = *reinterpret_cast<const f32x4*>(p1 + 4);
            bf16x8 a0, a1;
            #pragma unroll
            for (int j = 0; j < 4; ++j) {
                a0[j] = (bf16_t)v00[j]; a0[4+j] = (bf16_t)v01[j];
                a1[j] = (bf16_t)v10[j]; a1[4+j] = (bf16_t)v11[j];
            }
            #pragma unroll
            for (int ct = 0; ct < 4; ++ct) {
                acc[0][ct] = __builtin_amdgcn_mfma_f32_16x16x32_bf16(a0, Bf[ct][ks], acc[0][ct], 0, 0, 0);
                acc[1][ct] = __builtin_amdgcn_mfma_f32_16x16x32_bf16(a1, Bf[ct][ks], acc[1][ct], 0, 0, 0);
            }
        }

        #pragma unroll
        for (int rt = 0; rt < 2; ++rt)
            #pragma unroll
            for (int ct = 0; ct < 4; ++ct)
                #pragma unroll
                for (int r = 0; r < 4; ++r) {
                    const int row = n0 + rt*16 + lg*4 + r;
                    const int col = ct*16 + lr;
                    const float val = acc[rt][ct][r] + biasv[ct];
                    if (w < 3) kqv[(size_t)w * N_NODES * OUT_C + (size_t)row * OUT_C + col] = (bf16_t)val;
                    else       agg[(size_t)row * OUT_C + col] = val;
                }
    }
}

// ---------------- counting sort by dst ----------------
__global__ __launch_bounds__(256) void hist_kernel(const int* __restrict__ dst,
                                                   unsigned* __restrict__ cnt) {
    const int i = (blockIdx.x * 256 + threadIdx.x) * 4;
    if (i < N_EDGES) {
        int4 d = *reinterpret_cast<const int4*>(dst + i);
        atomicAdd(&cnt[d.x], 1u);
        atomicAdd(&cnt[d.y], 1u);
        atomicAdd(&cnt[d.z], 1u);
        atomicAdd(&cnt[d.w], 1u);
    }
}

__global__ __launch_bounds__(256) void scan1_kernel(const unsigned* __restrict__ cnt,
                                                    unsigned* __restrict__ bsum) {
    __shared__ unsigned s[256];
    const int b = blockIdx.x, t = threadIdx.x;
    const int i0 = b * 1024 + t * 4;
    unsigned x = 0;
    #pragma unroll
    for (int j = 0; j < 4; ++j)
        if (i0 + j < N_NODES) x += cnt[i0 + j];
    s[t] = x; __syncthreads();
    for (int d = 128; d > 0; d >>= 1) {
        if (t < d) s[t] += s[t + d];
        __syncthreads();
    }
    if (t == 0) bsum[b] = s[0];
}

__global__ void scan2_kernel(unsigned* __restrict__ bsum) {
    if (threadIdx.x == 0 && blockIdx.x == 0) {
        unsigned run = 0;
        for (int i = 0; i < NB_SCAN; ++i) { unsigned v = bsum[i]; bsum[i] = run; run += v; }
    }
}

__global__ __launch_bounds__(256) void scan3_kernel(const unsigned* __restrict__ cnt,
                                                    const unsigned* __restrict__ bsum,
                                                    unsigned* __restrict__ cursor) {
    __shared__ unsigned s[256];
    const int b = blockIdx.x, t = threadIdx.x;
    const int i0 = b * 1024 + t * 4;
    unsigned v[4]; unsigned x = 0;
    #pragma unroll
    for (int j = 0; j < 4; ++j) {
        v[j] = (i0 + j < N_NODES) ? cnt[i0 + j] : 0u;
        x += v[j];
    }
    s[t] = x; __syncthreads();
    for (int d = 1; d < 256; d <<= 1) {
        unsigned y = (t >= d) ? s[t - d] : 0u;
        __syncthreads();
        s[t] += y;
        __syncthreads();
    }
    unsigned excl = s[t] - x + bsum[b];
    #pragma unroll
    for (int j = 0; j < 4; ++j)
        if (i0 + j < N_NODES) { cursor[i0 + j] = excl; excl += v[j]; }
}

// scatter: sorted16[pos] = {eid, src, dst, 0}
__global__ __launch_bounds__(256) void scatter_kernel(const int* __restrict__ ei,
                                                      unsigned* __restrict__ cursor,
                                                      int4* __restrict__ sorted16) {
    const int i = (blockIdx.x * 256 + threadIdx.x) * 4;
    if (i < N_EDGES) {
        int4 s = *reinterpret_cast<const int4*>(ei + i);            // src
        int4 d = *reinterpret_cast<const int4*>(ei + N_EDGES + i);  // dst
        sorted16[atomicAdd(&cursor[d.x], 1u)] = make_int4(i + 0, s.x, d.x, 0);
        sorted16[atomicAdd(&cursor[d.y], 1u)] = make_int4(i + 1, s.y, d.y, 0);
        sorted16[atomicAdd(&cursor[d.z], 1u)] = make_int4(i + 2, s.z, d.z, 0);
        sorted16[atomicAdd(&cursor[d.w], 1u)] = make_int4(i + 3, s.w, d.w, 0);
    }
}

// ---------------- Kernel B: sorted tiles + LDS-staged wide gathers ----------------
// Per 16-edge tile: q/v rows fetched as dwordx4 (2 instrs per table, 8 rows each),
// transposed through per-wave LDS (stride-72 rows: 16B-aligned, <=2-way banks);
// k[dst] direct 2B gather (L1-resident, ~2 distinct rows/tile); W_edge in LDS.
__global__ __launch_bounds__(256) void edge_seg_kernel(
    const float* __restrict__ ea,
    const int4*  __restrict__ sorted16,
    const float* __restrict__ We, const float* __restrict__ be,
    const bf16_t* __restrict__ kqv,
    float* __restrict__ agg,
    float* __restrict__ out_ea)
{
    __shared__ bf16_t WeT[64][72];        // WeT[col][k] = We[k][col]
    __shared__ bf16_t qtab[4][16][72];    // per-wave staged q rows
    __shared__ bf16_t vtab[4][16][72];    // per-wave staged v rows

    const int tid = threadIdx.x;
    const int wv  = tid >> 6;
    const int l   = tid & 63;
    const int lr  = l & 15;
    const int lg  = l >> 4;
    const int row8 = l >> 3;   // 0..7
    const int part = l & 7;    // 0..7

    // stage WeT once (block-cooperative)
    for (int i = tid; i < 64*64; i += 256) {
        const int k = i >> 6, c = i & 63;
        WeT[c][k] = (bf16_t)We[i];
    }
    __syncthreads();

    float bev[4];
    #pragma unroll
    for (int ct = 0; ct < 4; ++ct) bev[ct] = be[ct*16 + lr];

    const bf16_t* kT = kqv;
    const bf16_t* qT = kqv + (size_t)N_NODES * OUT_C;
    const bf16_t* vT = kqv + (size_t)2 * N_NODES * OUT_C;

    const int wid0 = blockIdx.x * 4 + wv;
    const int nw   = gridDim.x * 4;
    const int NT   = N_EDGES / 16;

    for (int t = wid0; t < NT; t += nw) {
        const int e0 = t * 16;
        const int4 meta_l = sorted16[e0 + lr];   // slot lr's {eid, src, dst}

        // ---- A-fragment (slot = lr) + fused out_ea copy ----
        const int eidA = meta_l.x;
        bf16x8 a[2];
        #pragma unroll
        for (int ks = 0; ks < 2; ++ks) {
            const size_t off = (size_t)eidA * EDGE_D + ks*32 + lg*8;
            f32x4 v0 = *reinterpret_cast<const f32x4*>(ea + off);
            f32x4 v1 = *reinterpret_cast<const f32x4*>(ea + off + 4);
            *reinterpret_cast<f32x4*>(out_ea + off)     = v0;
            *reinterpret_cast<f32x4*>(out_ea + off + 4) = v1;
            #pragma unroll
            for (int j = 0; j < 4; ++j) { a[ks][j] = (bf16_t)v0[j]; a[ks][4+j] = (bf16_t)v1[j]; }
        }

        // ---- wide q/v row gathers -> LDS transpose ----
        const int src0 = __shfl(meta_l.y, row8);
        const int src1 = __shfl(meta_l.y, row8 + 8);
        uint4 gq0 = *reinterpret_cast<const uint4*>(qT + (size_t)src0 * OUT_C + part*8);
        uint4 gq1 = *reinterpret_cast<const uint4*>(qT + (size_t)src1 * OUT_C + part*8);
        uint4 gv0 = *reinterpret_cast<const uint4*>(vT + (size_t)src0 * OUT_C + part*8);
        uint4 gv1 = *reinterpret_cast<const uint4*>(vT + (size_t)src1 * OUT_C + part*8);
        *reinterpret_cast<uint4*>(&qtab[wv][row8    ][part*8]) = gq0;
        *reinterpret_cast<uint4*>(&qtab[wv][row8 + 8][part*8]) = gq1;
        *reinterpret_cast<uint4*>(&vtab[wv][row8    ][part*8]) = gv0;
        *reinterpret_cast<uint4*>(&vtab[wv][row8 + 8][part*8]) = gv1;

        // ---- MFMA e-projection, B-fragments from WeT ----
        f32x4 ep[4];
        #pragma unroll
        for (int ct = 0; ct < 4; ++ct) {
            bf16x8 b0 = *reinterpret_cast<const bf16x8*>(&WeT[ct*16 + lr][lg*8]);
            bf16x8 b1 = *reinterpret_cast<const bf16x8*>(&WeT[ct*16 + lr][32 + lg*8]);
            f32x4 z = (f32x4){0.f, 0.f, 0.f, 0.f};
            z = __builtin_amdgcn_mfma_f32_16x16x32_bf16(a[0], b0, z, 0, 0, 0);
            ep[ct] = __builtin_amdgcn_mfma_f32_16x16x32_bf16(a[1], b1, z, 0, 0, 0);
        }

        // dst per epilogue slot s = lg*4 + r (broadcast from slot lanes)
        int dR[4];
        #pragma unroll
        for (int r = 0; r < 4; ++r) dR[r] = __shfl(meta_l.z, lg*4 + r);
        const int d0 = dR[0], d1 = dR[1], d2 = dR[2], d3 = dR[3];

        // ---- gate + message ----
        float val[4][4];  // [r][ct]
        #pragma unroll
        for (int r = 0; r < 4; ++r) {
            const int s = lg*4 + r;
            #pragma unroll
            for (int ct = 0; ct < 4; ++ct) {
                const int col = ct*16 + lr;
                const float kd = (float)kT[(size_t)dR[r] * OUT_C + col];
                const float qs = (float)qtab[wv][s][col];
                const float vs = (float)vtab[wv][s][col];
                const float z  = kd + bev[ct] + qs + ep[ct][r];
                const float g  = 1.f / (1.f + __expf(-z));
                val[r][ct] = g * vs;
            }
        }

        // ---- in-lane inclusive segmented scan over r ----
        #pragma unroll
        for (int ct = 0; ct < 4; ++ct) {
            if (d1 == d0) val[1][ct] += val[0][ct];
            if (d2 == d1) val[2][ct] += val[1][ct];
            if (d3 == d2) val[3][ct] += val[2][ct];
        }

        // ---- cross-lane-group segmented scan on (S, B) monoid ----
        const int prev_d3 = __shfl(d3, l - 16);
        const int h  = (lg == 0) || (d0 != prev_d3);
        int Bs = h || (d0 != d3);
        float S[4];
        #pragma unroll
        for (int ct = 0; ct < 4; ++ct) S[ct] = val[3][ct];

        {
            float p0 = __shfl(S[0], l-16), p1 = __shfl(S[1], l-16),
                  p2 = __shfl(S[2], l-16), p3 = __shfl(S[3], l-16);
            int  pB = __shfl(Bs, l-16);
            if (lg >= 1) {
                if (!Bs) { S[0] += p0; S[1] += p1; S[2] += p2; S[3] += p3; }
                Bs |= pB;
            }
        }
        {
            float p0 = __shfl(S[0], l-32), p1 = __shfl(S[1], l-32),
                  p2 = __shfl(S[2], l-32), p3 = __shfl(S[3], l-32);
            int  pB = __shfl(Bs, l-32);
            if (lg >= 2) {
                if (!Bs) { S[0] += p0; S[1] += p1; S[2] += p2; S[3] += p3; }
                Bs |= pB;
            }
        }

        float C[4];
        #pragma unroll
        for (int ct = 0; ct < 4; ++ct) C[ct] = __shfl(S[ct], l - 16);

        if (!h) {
            #pragma unroll
            for (int r = 0; r < 4; ++r)
                if (dR[r] == d0) {
                    #pragma unroll
                    for (int ct = 0; ct < 4; ++ct) val[r][ct] += C[ct];
                }
        }

        const int next_d0 = __shfl(d0, l + 16);
        bool lastR[4];
        lastR[0] = (d1 != d0);
        lastR[1] = (d2 != d1);
        lastR[2] = (d3 != d2);
        lastR[3] = (lg == 3) ? true : (next_d0 != d3);

        #pragma unroll
        for (int r = 0; r < 4; ++r) {
            if (lastR[r]) {
                float* row = agg + (size_t)dR[r] * OUT_C + lr;
                #pragma unroll
                for (int ct = 0; ct < 4; ++ct)
                    atomicAdd(row + ct*16, val[r][ct]);
            }
        }
    }
}

// ---------------- Kernel C: finalize ----------------
__global__ __launch_bounds__(256) void finalize_kernel(
    const float* __restrict__ agg,
    const float* __restrict__ u,
    float* __restrict__ out_node,
    float* __restrict__ out_u)
{
    const int gid   = blockIdx.x * blockDim.x + threadIdx.x;
    const int total = N_NODES * OUT_C / 4;
    for (int i = gid; i < total; i += gridDim.x * blockDim.x) {
        f32x4 v = *reinterpret_cast<const f32x4*>(agg + (size_t)i * 4);
        f32x4 o;
        #pragma unroll
        for (int j = 0; j < 4; ++j) o[j] = v[j] > 0.f ? v[j] : 0.f;
        *reinterpret_cast<f32x4*>(out_node + (size_t)i * 4) = o;
    }
    if (gid < 64) out_u[gid] = u[gid];
}

extern "C" void kernel_launch(void* const* d_in, const int* in_sizes, int n_in,
                              void* d_out, int out_size, void* d_ws, size_t ws_size,
                              hipStream_t stream) {
    const float* x  = (const float*)d_in[0];
    const int*   ei = (const int*)  d_in[1];
    const float* ea = (const float*)d_in[2];
    const float* u  = (const float*)d_in[3];
    const float* Wk = (const float*)d_in[4];
    const float* bk = (const float*)d_in[5];
    const float* Wq = (const float*)d_in[6];
    const float* bq = (const float*)d_in[7];
    const float* Wv = (const float*)d_in[8];
    const float* bv = (const float*)d_in[9];
    const float* We = (const float*)d_in[10];
    const float* be = (const float*)d_in[11];
    const float* Ws = (const float*)d_in[12];
    const float* bs = (const float*)d_in[13];

    float* out      = (float*)d_out;
    float* out_node = out;
    float* out_ea   = out + (size_t)N_NODES * OUT_C;
    float* out_u    = out + (size_t)N_NODES * OUT_C + (size_t)N_EDGES * EDGE_D;

    // ws layout
    char* w = (char*)d_ws;
    bf16_t*   kqv      = (bf16_t*)w;                     // 38,400,000 B
    float*    agg      = (float*)(w + 38400000);         // 25,600,000 B -> 64,000,000
    unsigned* cnt      = (unsigned*)(w + 64000000);      //    400,000 B -> 64,400,000
    unsigned* bsum     = (unsigned*)(w + 64400000);      //        512 B -> 64,400,512
    int4*     sorted16 = (int4*)(w + 64400512);          // 25,600,000 B -> 90,000,512

    const int* dst = ei + N_EDGES;

    node_gemm_kernel<<<1024, 256, 0, stream>>>(x, Wk, bk, Wq, bq, Wv, bv, Ws, bs, kqv, agg);
    hipMemsetAsync(cnt, 0, N_NODES * sizeof(unsigned), stream);
    hist_kernel<<<1563, 256, 0, stream>>>(dst, cnt);
    scan1_kernel<<<NB_SCAN, 256, 0, stream>>>(cnt, bsum);
    scan2_kernel<<<1, 64, 0, stream>>>(bsum);
    scan3_kernel<<<NB_SCAN, 256, 0, stream>>>(cnt, bsum, cnt /*cursor (in-place)*/);
    scatter_kernel<<<1563, 256, 0, stream>>>(ei, cnt, sorted16);
    edge_seg_kernel<<<2048, 256, 0, stream>>>(ea, sorted16, We, be, kqv, agg, out_ea);
    finalize_kernel<<<2048, 256, 0, stream>>>(agg, u, out_node, out_u);
}